// Round 4
// baseline (614.333 us; speedup 1.0000x reference)
//
#include <hip/hip_runtime.h>
#include <math.h>

#define NEG_SLOPE 0.2f

static inline int cdiv(int a, int b) { return (a + b - 1) / b; }

// ---------------- CSR build: LDS radix partition by dst bucket --------------
// bucket = 256 consecutive dst nodes; packed entry = (src<<8) | (dst&255).
// Requires N <= 65536 (here N=50000) and NBK <= 256 (196).
#define BCAP 12288            // per-bucket slab capacity (avg fill ~8450)
#define PT_THREADS 512
#define PT_EPT 16
#define PT_CHUNK (PT_THREADS * PT_EPT)   // 8192 edges per block

__global__ __launch_bounds__(PT_THREADS)
void partition_kernel(const int* __restrict__ src, const int* __restrict__ dst,
                      unsigned* __restrict__ gcursor, unsigned* __restrict__ slab,
                      int E, int ET, int NBK) {
    __shared__ int hist[256];
    __shared__ int lbase[256];
    __shared__ int lcur[256];
    __shared__ int gbase[256];
    __shared__ unsigned stage[PT_CHUNK];
    __shared__ unsigned char binof[PT_CHUNK];

    int base = blockIdx.x * PT_CHUNK;
    int cnt = min(PT_CHUNK, ET - base);

    unsigned vals[PT_EPT];
    short bins[PT_EPT];

    for (int i = threadIdx.x; i < 256; i += PT_THREADS) hist[i] = 0;
    __syncthreads();

#pragma unroll
    for (int i = 0; i < PT_EPT; ++i) {
        int e = base + threadIdx.x + i * PT_THREADS;
        bins[i] = -1;
        if (e < ET) {
            int s = (e < E) ? src[e] : (e - E);
            int d = (e < E) ? dst[e] : (e - E);
            int b = d >> 8;
            vals[i] = ((unsigned)s << 8) | (unsigned)(d & 255);
            bins[i] = (short)b;
            atomicAdd(&hist[b], 1);
        }
    }
    __syncthreads();
    // inclusive scan of hist (tid<256), then convert to exclusive
    if (threadIdx.x < 256) lbase[threadIdx.x] = hist[threadIdx.x];
    __syncthreads();
    for (int off = 1; off < 256; off <<= 1) {
        int t = 0;
        if (threadIdx.x < 256 && threadIdx.x >= off) t = lbase[threadIdx.x - off];
        __syncthreads();
        if (threadIdx.x < 256) lbase[threadIdx.x] += t;
        __syncthreads();
    }
    if (threadIdx.x < 256) {
        lbase[threadIdx.x] -= hist[threadIdx.x];   // exclusive
        lcur[threadIdx.x] = lbase[threadIdx.x];
        gbase[threadIdx.x] = ((int)threadIdx.x < NBK && hist[threadIdx.x] > 0)
            ? (int)atomicAdd(&gcursor[threadIdx.x], (unsigned)hist[threadIdx.x]) : 0;
    }
    __syncthreads();
#pragma unroll
    for (int i = 0; i < PT_EPT; ++i) {
        if (bins[i] >= 0) {
            int p = atomicAdd(&lcur[bins[i]], 1);
            stage[p] = vals[i];
            binof[p] = (unsigned char)bins[i];
        }
    }
    __syncthreads();
    // write each bucket's run contiguously (bursts of ~cnt/NBK entries)
    for (int j = threadIdx.x; j < cnt; j += PT_THREADS) {
        int b = binof[j];
        int idx = gbase[b] + (j - lbase[b]);
        if (idx < BCAP) slab[(size_t)b * BCAP + idx] = stage[j];
    }
}

// one block per bucket: degree + local offsets + stable in-place sort by dst
__global__ __launch_bounds__(512)
void finalize_kernel(const unsigned* __restrict__ gcursor, unsigned* __restrict__ slab,
                     int* __restrict__ offs, int* __restrict__ deg, int N) {
    __shared__ int lhist[256];
    __shared__ int loff[256];
    __shared__ int lcur[256];
    __shared__ unsigned stage[BCAP];
    int b = blockIdx.x;
    int cnt = min((int)gcursor[b], BCAP);
    int d0 = b << 8;
    int nd = min(256, N - d0);
    size_t sb = (size_t)b * BCAP;

    for (int i = threadIdx.x; i < 256; i += 512) lhist[i] = 0;
    __syncthreads();
    for (int i = threadIdx.x; i < cnt; i += 512)
        atomicAdd(&lhist[slab[sb + i] & 255u], 1);
    __syncthreads();
    if (threadIdx.x < 256) loff[threadIdx.x] = lhist[threadIdx.x];
    __syncthreads();
    for (int off = 1; off < 256; off <<= 1) {
        int t = 0;
        if (threadIdx.x < 256 && threadIdx.x >= off) t = loff[threadIdx.x - off];
        __syncthreads();
        if (threadIdx.x < 256) loff[threadIdx.x] += t;
        __syncthreads();
    }
    if (threadIdx.x < 256) {
        loff[threadIdx.x] -= lhist[threadIdx.x];   // exclusive
        lcur[threadIdx.x] = loff[threadIdx.x];
        if ((int)threadIdx.x < nd) {
            offs[d0 + threadIdx.x] = (int)sb + loff[threadIdx.x];
            deg[d0 + threadIdx.x] = lhist[threadIdx.x];
        }
    }
    __syncthreads();
    for (int i = threadIdx.x; i < cnt; i += 512) {
        unsigned v = slab[sb + i];
        int p = atomicAdd(&lcur[v & 255u], 1);
        stage[p] = v >> 8;
    }
    __syncthreads();
    for (int i = threadIdx.x; i < cnt; i += 512)
        slab[sb + i] = stage[i];
}

// ============ dense GEMM + fused attention-logit epilogue ===================
template <int CIN, int COUT, int H>
__global__ void gemm_logits_kernel(const float* __restrict__ in, const float* __restrict__ W,
                                   const float* __restrict__ a_s, const float* __restrict__ a_d,
                                   float* __restrict__ out, float* __restrict__ als,
                                   float* __restrict__ ald, int N) {
    constexpr int D = COUT / H;
    constexpr int TPN = COUT / 4;    // threads per node
    constexpr int NPB = 256 / TPN;   // nodes per block
    __shared__ float xs[NPB * CIN];
    __shared__ float lsum[2][NPB][H];
    int n0 = blockIdx.x * NPB;
    for (int i = threadIdx.x * 4; i < NPB * CIN; i += 256 * 4) {
        int n = n0 + i / CIN;
        float4 v = make_float4(0.f, 0.f, 0.f, 0.f);
        if (n < N) v = *(const float4*)&in[(size_t)n0 * CIN + i];
        *(float4*)&xs[i] = v;
    }
    for (int i = threadIdx.x; i < 2 * NPB * H; i += 256) ((float*)lsum)[i] = 0.f;
    __syncthreads();
    int tn = threadIdx.x / TPN;
    int tc = (threadIdx.x % TPN) * 4;
    int n = n0 + tn;
    if (n < N) {
        const float* xr = xs + tn * CIN;
        float4 a = make_float4(0.f, 0.f, 0.f, 0.f);
#pragma unroll 8
        for (int k = 0; k < CIN; ++k) {
            float xv = xr[k];
            float4 wv = *(const float4*)&W[k * COUT + tc];
            a.x = fmaf(xv, wv.x, a.x);
            a.y = fmaf(xv, wv.y, a.y);
            a.z = fmaf(xv, wv.z, a.z);
            a.w = fmaf(xv, wv.w, a.w);
        }
        *(float4*)&out[(size_t)n * COUT + tc] = a;
        int h = tc / D;
        int dd = tc % D;
        const float* asr = a_s + h * D + dd;
        const float* adr = a_d + h * D + dd;
        float p1 = a.x * asr[0] + a.y * asr[1] + a.z * asr[2] + a.w * asr[3];
        float p2 = a.x * adr[0] + a.y * adr[1] + a.z * adr[2] + a.w * adr[3];
        atomicAdd(&lsum[0][tn][h], p1);
        atomicAdd(&lsum[1][tn][h], p2);
    }
    __syncthreads();
    for (int i = threadIdx.x; i < NPB * H; i += 256) {
        int tn2 = i / H, h2 = i % H;
        int n2 = n0 + tn2;
        if (n2 < N) {
            als[n2 * H + h2] = lsum[0][tn2][h2];
            ald[n2 * H + h2] = lsum[1][tn2][h2];
        }
    }
}

// ===== fused per-node GAT aggregate: online softmax + weighted sum =========
template <int H, int D, bool RELU>
__global__ void gat_aggregate(const float* __restrict__ hfeat,
                              const float* __restrict__ als, const float* __restrict__ ald,
                              const int* __restrict__ offs, const int* __restrict__ deg,
                              const int* __restrict__ csr_src,
                              const float* __restrict__ bias,
                              float* __restrict__ out, int N) {
    constexpr int HD = H * D;
    constexpr int NPW = 64 / HD;  // nodes per wave
    int lane = threadIdx.x & 63;
    int wid = threadIdx.x >> 6;
    int wavesPerBlock = blockDim.x >> 6;
    int grp = lane / HD;
    int c = lane % HD;
    int h = c / D;
    long node = ((long)blockIdx.x * wavesPerBlock + wid) * NPW + grp;
    if (node >= N) return;
    int row = offs[node];
    int cnt = deg[node];
    if constexpr (NPW == 1) {     // node wave-uniform -> keep CSR walk scalar
        row = __builtin_amdgcn_readfirstlane(row);
        cnt = __builtin_amdgcn_readfirstlane(cnt);
    }
    float xd = ald[node * H + h];
    float m = -INFINITY, s = 0.f, acc = 0.f;
#pragma unroll 4
    for (int k = 0; k < cnt; ++k) {
        int sn = csr_src[row + k];
        if constexpr (NPW == 1) sn = __builtin_amdgcn_readfirstlane(sn);
        float x = als[sn * H + h] + xd;
        x = (x > 0.f) ? x : NEG_SLOPE * x;
        float hv = hfeat[(size_t)sn * HD + c];
        float mn = fmaxf(m, x);
        float sc = __expf(m - mn);
        float w = __expf(x - mn);
        s = s * sc + w;
        acc = acc * sc + w * hv;
        m = mn;
    }
    float v = acc / s + bias[c];
    if (RELU) v = fmaxf(v, 0.f);
    out[(size_t)node * HD + c] = v;
}

// ============================================================================

extern "C" void kernel_launch(void* const* d_in, const int* in_sizes, int n_in,
                              void* d_out, int out_size, void* d_ws, size_t ws_size,
                              hipStream_t stream) {
    const float* x   = (const float*)d_in[0];
    const int*   ei  = (const int*)d_in[1];
    const float* W1  = (const float*)d_in[2];
    const float* a1s = (const float*)d_in[3];
    const float* a1d = (const float*)d_in[4];
    const float* b1  = (const float*)d_in[5];
    const float* W2  = (const float*)d_in[6];
    const float* a2s = (const float*)d_in[7];
    const float* a2d = (const float*)d_in[8];
    const float* b2  = (const float*)d_in[9];
    const float* W3  = (const float*)d_in[10];
    const float* a3s = (const float*)d_in[11];
    const float* a3d = (const float*)d_in[12];
    const float* b3  = (const float*)d_in[13];
    const float* W4  = (const float*)d_in[14];
    const float* a4s = (const float*)d_in[15];
    const float* a4d = (const float*)d_in[16];
    const float* b4  = (const float*)d_in[17];

    const int N = in_sizes[0] / 128;  // 50000
    const int E = in_sizes[1] / 2;    // 1600000
    const int ET = E + N;             // + self loops
    const int* src = ei;
    const int* dst = ei + E;
    const int NBK = (N + 255) >> 8;   // 196 buckets of 256 dst nodes

    // ---- workspace layout ----
    float* hb    = (float*)d_ws;                    // N*64
    float* bufA  = hb + (size_t)N * 64;             // N*64
    float* als   = bufA + (size_t)N * 64;           // N*8
    float* ald   = als + (size_t)N * 8;             // N*8
    int* offs    = (int*)(ald + (size_t)N * 8);     // N
    int* deg     = offs + N;                        // N
    unsigned* gcursor = (unsigned*)(deg + N);       // 256 (memset 0)
    unsigned* slab = gcursor + 256;                 // NBK*BCAP (csr in place)
    float* out = (float*)d_out;                     // N*16

    const int TB = 256;

    // ---- build dst-CSR: radix partition + per-bucket finalize ----
    hipMemsetAsync(gcursor, 0, 256 * 4, stream);
    partition_kernel<<<cdiv(ET, PT_CHUNK), PT_THREADS, 0, stream>>>(src, dst, gcursor, slab, E, ET, NBK);
    finalize_kernel<<<NBK, 512, 0, stream>>>(gcursor, slab, offs, deg, N);
    const int* csr_src = (const int*)slab;

    // ---- layer 1: x[N,128] -> hb -> bufA ----
    gemm_logits_kernel<128, 64, 8><<<cdiv(N, 16), TB, 0, stream>>>(x, W1, a1s, a1d, hb, als, ald, N);
    gat_aggregate<8, 8, true><<<cdiv(N, 4), TB, 0, stream>>>(hb, als, ald, offs, deg, csr_src, b1, bufA, N);

    // ---- layer 2: bufA -> hb -> bufA ----
    gemm_logits_kernel<64, 64, 8><<<cdiv(N, 16), TB, 0, stream>>>(bufA, W2, a2s, a2d, hb, als, ald, N);
    gat_aggregate<8, 8, true><<<cdiv(N, 4), TB, 0, stream>>>(hb, als, ald, offs, deg, csr_src, b2, bufA, N);

    // ---- layer 3: bufA -> hb -> bufA ----
    gemm_logits_kernel<64, 64, 8><<<cdiv(N, 16), TB, 0, stream>>>(bufA, W3, a3s, a3d, hb, als, ald, N);
    gat_aggregate<8, 8, true><<<cdiv(N, 4), TB, 0, stream>>>(hb, als, ald, offs, deg, csr_src, b3, bufA, N);

    // ---- layer 4: bufA -> hb -> d_out (H=1, D=16, no relu) ----
    gemm_logits_kernel<64, 16, 1><<<cdiv(N, 64), TB, 0, stream>>>(bufA, W4, a4s, a4d, hb, als, ald, N);
    gat_aggregate<1, 16, false><<<cdiv(N, 16), TB, 0, stream>>>(hb, als, ald, offs, deg, csr_src, b4, out, N);
}

// Round 6
// 530.445 us; speedup vs baseline: 1.1581x; 1.1581x over previous
//
#include <hip/hip_runtime.h>
#include <math.h>

#define NEG_SLOPE 0.2f

static inline int cdiv(int a, int b) { return (a + b - 1) / b; }

// ---------------- CSR build: LDS radix partition by dst bucket --------------
// bucket = 256 consecutive dst nodes; packed entry = (src<<8) | (dst&255).
// Requires N <= 65536 (here N=50000) and NBK <= 256 (196).
#define BCAP 12288            // per-bucket slab capacity (avg fill ~8450)
#define PT_THREADS 512
#define PT_EPT 16
#define PT_CHUNK (PT_THREADS * PT_EPT)   // 8192 edges per block

__global__ __launch_bounds__(PT_THREADS)
void partition_kernel(const int* __restrict__ src, const int* __restrict__ dst,
                      unsigned* __restrict__ gcursor, unsigned* __restrict__ slab,
                      int E, int ET, int NBK) {
    __shared__ int hist[256];
    __shared__ int lbase[256];
    __shared__ int lcur[256];
    __shared__ int gbase[256];
    __shared__ unsigned stage[PT_CHUNK];
    __shared__ unsigned char binof[PT_CHUNK];

    int base = blockIdx.x * PT_CHUNK;
    int cnt = min(PT_CHUNK, ET - base);

    unsigned vals[PT_EPT];
    short bins[PT_EPT];

    for (int i = threadIdx.x; i < 256; i += PT_THREADS) hist[i] = 0;
    __syncthreads();

#pragma unroll
    for (int i = 0; i < PT_EPT; ++i) {
        int e = base + threadIdx.x + i * PT_THREADS;
        bins[i] = -1;
        if (e < ET) {
            int s = (e < E) ? src[e] : (e - E);
            int d = (e < E) ? dst[e] : (e - E);
            int b = d >> 8;
            vals[i] = ((unsigned)s << 8) | (unsigned)(d & 255);
            bins[i] = (short)b;
            atomicAdd(&hist[b], 1);
        }
    }
    __syncthreads();
    if (threadIdx.x < 256) lbase[threadIdx.x] = hist[threadIdx.x];
    __syncthreads();
    for (int off = 1; off < 256; off <<= 1) {
        int t = 0;
        if (threadIdx.x < 256 && threadIdx.x >= off) t = lbase[threadIdx.x - off];
        __syncthreads();
        if (threadIdx.x < 256) lbase[threadIdx.x] += t;
        __syncthreads();
    }
    if (threadIdx.x < 256) {
        lbase[threadIdx.x] -= hist[threadIdx.x];   // exclusive
        lcur[threadIdx.x] = lbase[threadIdx.x];
        gbase[threadIdx.x] = ((int)threadIdx.x < NBK && hist[threadIdx.x] > 0)
            ? (int)atomicAdd(&gcursor[threadIdx.x], (unsigned)hist[threadIdx.x]) : 0;
    }
    __syncthreads();
#pragma unroll
    for (int i = 0; i < PT_EPT; ++i) {
        if (bins[i] >= 0) {
            int p = atomicAdd(&lcur[bins[i]], 1);
            stage[p] = vals[i];
            binof[p] = (unsigned char)bins[i];
        }
    }
    __syncthreads();
    for (int j = threadIdx.x; j < cnt; j += PT_THREADS) {
        int b = binof[j];
        int idx = gbase[b] + (j - lbase[b]);
        if (idx < BCAP) slab[(size_t)b * BCAP + idx] = stage[j];
    }
}

// one block per bucket: degree + local offsets + stable in-place sort by dst
__global__ __launch_bounds__(512)
void finalize_kernel(const unsigned* __restrict__ gcursor, unsigned* __restrict__ slab,
                     int* __restrict__ offs, int* __restrict__ deg, int N) {
    __shared__ int lhist[256];
    __shared__ int loff[256];
    __shared__ int lcur[256];
    __shared__ unsigned stage[BCAP];
    int b = blockIdx.x;
    int cnt = min((int)gcursor[b], BCAP);
    int d0 = b << 8;
    int nd = min(256, N - d0);
    size_t sb = (size_t)b * BCAP;

    for (int i = threadIdx.x; i < 256; i += 512) lhist[i] = 0;
    __syncthreads();
    for (int i = threadIdx.x; i < cnt; i += 512)
        atomicAdd(&lhist[slab[sb + i] & 255u], 1);
    __syncthreads();
    if (threadIdx.x < 256) loff[threadIdx.x] = lhist[threadIdx.x];
    __syncthreads();
    for (int off = 1; off < 256; off <<= 1) {
        int t = 0;
        if (threadIdx.x < 256 && threadIdx.x >= off) t = loff[threadIdx.x - off];
        __syncthreads();
        if (threadIdx.x < 256) loff[threadIdx.x] += t;
        __syncthreads();
    }
    if (threadIdx.x < 256) {
        loff[threadIdx.x] -= lhist[threadIdx.x];   // exclusive
        lcur[threadIdx.x] = loff[threadIdx.x];
        if ((int)threadIdx.x < nd) {
            offs[d0 + threadIdx.x] = (int)sb + loff[threadIdx.x];
            deg[d0 + threadIdx.x] = lhist[threadIdx.x];
        }
    }
    __syncthreads();
    for (int i = threadIdx.x; i < cnt; i += 512) {
        unsigned v = slab[sb + i];
        int p = atomicAdd(&lcur[v & 255u], 1);
        stage[p] = v >> 8;
    }
    __syncthreads();
    for (int i = threadIdx.x; i < cnt; i += 512)
        slab[sb + i] = stage[i];
}

// ============ dense GEMM + fused attention-logit epilogue ===================
template <int CIN, int COUT, int H>
__global__ void gemm_logits_kernel(const float* __restrict__ in, const float* __restrict__ W,
                                   const float* __restrict__ a_s, const float* __restrict__ a_d,
                                   float* __restrict__ out, float* __restrict__ als,
                                   float* __restrict__ ald, int N) {
    constexpr int D = COUT / H;
    constexpr int TPN = COUT / 4;    // threads per node
    constexpr int NPB = 256 / TPN;   // nodes per block
    __shared__ float xs[NPB * CIN];
    __shared__ float lsum[2][NPB][H];
    int n0 = blockIdx.x * NPB;
    for (int i = threadIdx.x * 4; i < NPB * CIN; i += 256 * 4) {
        int n = n0 + i / CIN;
        float4 v = make_float4(0.f, 0.f, 0.f, 0.f);
        if (n < N) v = *(const float4*)&in[(size_t)n0 * CIN + i];
        *(float4*)&xs[i] = v;
    }
    for (int i = threadIdx.x; i < 2 * NPB * H; i += 256) ((float*)lsum)[i] = 0.f;
    __syncthreads();
    int tn = threadIdx.x / TPN;
    int tc = (threadIdx.x % TPN) * 4;
    int n = n0 + tn;
    if (n < N) {
        const float* xr = xs + tn * CIN;
        float4 a = make_float4(0.f, 0.f, 0.f, 0.f);
#pragma unroll 8
        for (int k = 0; k < CIN; ++k) {
            float xv = xr[k];
            float4 wv = *(const float4*)&W[k * COUT + tc];
            a.x = fmaf(xv, wv.x, a.x);
            a.y = fmaf(xv, wv.y, a.y);
            a.z = fmaf(xv, wv.z, a.z);
            a.w = fmaf(xv, wv.w, a.w);
        }
        *(float4*)&out[(size_t)n * COUT + tc] = a;
        int h = tc / D;
        int dd = tc % D;
        const float* asr = a_s + h * D + dd;
        const float* adr = a_d + h * D + dd;
        float p1 = a.x * asr[0] + a.y * asr[1] + a.z * asr[2] + a.w * asr[3];
        float p2 = a.x * adr[0] + a.y * adr[1] + a.z * adr[2] + a.w * adr[3];
        atomicAdd(&lsum[0][tn][h], p1);
        atomicAdd(&lsum[1][tn][h], p2);
    }
    __syncthreads();
    for (int i = threadIdx.x; i < NPB * H; i += 256) {
        int tn2 = i / H, h2 = i % H;
        int n2 = n0 + tn2;
        if (n2 < N) {
            als[n2 * H + h2] = lsum[0][tn2][h2];
            ald[n2 * H + h2] = lsum[1][tn2][h2];
        }
    }
}

// ===== fused per-node GAT: phase1 (m,s) lane-parallel, phase2 stream-accum ==
// ONE WAVE PER NODE (grid must supply N waves).
// Phase 1: lane = (edge_slot, head); per-lane online (m,s) over cnt/ES edges,
// then shfl_xor merge -> per-head (m,s).
// Phase 2: lane = output channel c; with m known, iterations are independent
// -> 4-wide unrolled, 4 accumulators, loads pipeline.
template <int H, int D, bool RELU>
__global__ void gat_node_kernel(const float* __restrict__ hfeat,
                                const float* __restrict__ als, const float* __restrict__ ald,
                                const int* __restrict__ offs, const int* __restrict__ deg,
                                const int* __restrict__ csr_src,
                                const float* __restrict__ bias,
                                float* __restrict__ out, int N) {
    constexpr int HD = H * D;
    constexpr int ES = 64 / H;    // phase-1 edge slots
    constexpr int EG = 64 / HD;   // phase-2 edge groups
    int lane = threadIdx.x & 63;
    int wid = threadIdx.x >> 6;
    int node = blockIdx.x * (blockDim.x >> 6) + wid;
    if (node >= N) return;
    int row = __builtin_amdgcn_readfirstlane(offs[node]);
    int cnt = __builtin_amdgcn_readfirstlane(deg[node]);

    // ---------- phase 1: per-head (m, s) ----------
    int h1 = lane & (H - 1);
    float xd1 = ald[node * H + h1];
    float ml = -INFINITY, sl = 0.f;
    for (int k = lane / H; k < cnt; k += ES) {
        int sn = csr_src[row + k];
        float x = als[sn * H + h1] + xd1;
        x = (x > 0.f) ? x : NEG_SLOPE * x;
        float mn = fmaxf(ml, x);
        sl = sl * __expf(ml - mn) + __expf(x - mn);
        ml = mn;
    }
    for (int off = H; off < 64; off <<= 1) {
        float mo = __shfl_xor(ml, off);
        float so = __shfl_xor(sl, off);
        float mn = fmaxf(ml, mo);
        float t1 = (ml > -INFINITY) ? sl * __expf(ml - mn) : 0.f;
        float t2 = (mo > -INFINITY) ? so * __expf(mo - mn) : 0.f;
        sl = t1 + t2;
        ml = mn;
    }

    // ---------- phase 2: stream accumulate ----------
    int c = lane & (HD - 1);
    int h2 = c / D;
    float m2 = __shfl(ml, h2);
    float s2 = __shfl(sl, h2);
    float xd2 = ald[node * H + h2];
    float a0 = 0.f, a1 = 0.f, a2 = 0.f, a3 = 0.f;
    int k = lane / HD;  // edge-group index
    for (; k + 3 * EG < cnt; k += 4 * EG) {
        int sn0 = csr_src[row + k];
        int sn1 = csr_src[row + k + EG];
        int sn2 = csr_src[row + k + 2 * EG];
        int sn3 = csr_src[row + k + 3 * EG];
        if constexpr (EG == 1) {
            sn0 = __builtin_amdgcn_readfirstlane(sn0);
            sn1 = __builtin_amdgcn_readfirstlane(sn1);
            sn2 = __builtin_amdgcn_readfirstlane(sn2);
            sn3 = __builtin_amdgcn_readfirstlane(sn3);
        }
        float x0 = als[sn0 * H + h2] + xd2;
        float x1 = als[sn1 * H + h2] + xd2;
        float x2 = als[sn2 * H + h2] + xd2;
        float x3 = als[sn3 * H + h2] + xd2;
        x0 = (x0 > 0.f) ? x0 : NEG_SLOPE * x0;
        x1 = (x1 > 0.f) ? x1 : NEG_SLOPE * x1;
        x2 = (x2 > 0.f) ? x2 : NEG_SLOPE * x2;
        x3 = (x3 > 0.f) ? x3 : NEG_SLOPE * x3;
        float w0 = __expf(x0 - m2);
        float w1 = __expf(x1 - m2);
        float w2 = __expf(x2 - m2);
        float w3 = __expf(x3 - m2);
        a0 = fmaf(w0, hfeat[(size_t)sn0 * HD + c], a0);
        a1 = fmaf(w1, hfeat[(size_t)sn1 * HD + c], a1);
        a2 = fmaf(w2, hfeat[(size_t)sn2 * HD + c], a2);
        a3 = fmaf(w3, hfeat[(size_t)sn3 * HD + c], a3);
    }
    for (; k < cnt; k += EG) {
        int sn = csr_src[row + k];
        if constexpr (EG == 1) sn = __builtin_amdgcn_readfirstlane(sn);
        float x = als[sn * H + h2] + xd2;
        x = (x > 0.f) ? x : NEG_SLOPE * x;
        a0 = fmaf(__expf(x - m2), hfeat[(size_t)sn * HD + c], a0);
    }
    float acc = (a0 + a1) + (a2 + a3);
    for (int off = HD; off < 64; off <<= 1) acc += __shfl_xor(acc, off);
    if (lane < HD) {
        float v = acc / s2 + bias[c];
        if (RELU) v = fmaxf(v, 0.f);
        out[(size_t)node * HD + c] = v;
    }
}

// ============================================================================

extern "C" void kernel_launch(void* const* d_in, const int* in_sizes, int n_in,
                              void* d_out, int out_size, void* d_ws, size_t ws_size,
                              hipStream_t stream) {
    const float* x   = (const float*)d_in[0];
    const int*   ei  = (const int*)d_in[1];
    const float* W1  = (const float*)d_in[2];
    const float* a1s = (const float*)d_in[3];
    const float* a1d = (const float*)d_in[4];
    const float* b1  = (const float*)d_in[5];
    const float* W2  = (const float*)d_in[6];
    const float* a2s = (const float*)d_in[7];
    const float* a2d = (const float*)d_in[8];
    const float* b2  = (const float*)d_in[9];
    const float* W3  = (const float*)d_in[10];
    const float* a3s = (const float*)d_in[11];
    const float* a3d = (const float*)d_in[12];
    const float* b3  = (const float*)d_in[13];
    const float* W4  = (const float*)d_in[14];
    const float* a4s = (const float*)d_in[15];
    const float* a4d = (const float*)d_in[16];
    const float* b4  = (const float*)d_in[17];

    const int N = in_sizes[0] / 128;  // 50000
    const int E = in_sizes[1] / 2;    // 1600000
    const int ET = E + N;             // + self loops
    const int* src = ei;
    const int* dst = ei + E;
    const int NBK = (N + 255) >> 8;   // 196 buckets of 256 dst nodes

    // ---- workspace layout ----
    float* hb    = (float*)d_ws;                    // N*64
    float* bufA  = hb + (size_t)N * 64;             // N*64
    float* als   = bufA + (size_t)N * 64;           // N*8
    float* ald   = als + (size_t)N * 8;             // N*8
    int* offs    = (int*)(ald + (size_t)N * 8);     // N
    int* deg     = offs + N;                        // N
    unsigned* gcursor = (unsigned*)(deg + N);       // 256 (memset 0)
    unsigned* slab = gcursor + 256;                 // NBK*BCAP (csr in place)
    float* out = (float*)d_out;                     // N*16

    const int TB = 256;
    const int NODE_BLOCKS = cdiv(N, 4);  // one wave per node, 4 waves/block

    // ---- build dst-CSR: radix partition + per-bucket finalize ----
    hipMemsetAsync(gcursor, 0, 256 * 4, stream);
    partition_kernel<<<cdiv(ET, PT_CHUNK), PT_THREADS, 0, stream>>>(src, dst, gcursor, slab, E, ET, NBK);
    finalize_kernel<<<NBK, 512, 0, stream>>>(gcursor, slab, offs, deg, N);
    const int* csr_src = (const int*)slab;

    // ---- layer 1: x[N,128] -> hb -> bufA ----
    gemm_logits_kernel<128, 64, 8><<<cdiv(N, 16), TB, 0, stream>>>(x, W1, a1s, a1d, hb, als, ald, N);
    gat_node_kernel<8, 8, true><<<NODE_BLOCKS, TB, 0, stream>>>(hb, als, ald, offs, deg, csr_src, b1, bufA, N);

    // ---- layer 2: bufA -> hb -> bufA ----
    gemm_logits_kernel<64, 64, 8><<<cdiv(N, 16), TB, 0, stream>>>(bufA, W2, a2s, a2d, hb, als, ald, N);
    gat_node_kernel<8, 8, true><<<NODE_BLOCKS, TB, 0, stream>>>(hb, als, ald, offs, deg, csr_src, b2, bufA, N);

    // ---- layer 3: bufA -> hb -> bufA ----
    gemm_logits_kernel<64, 64, 8><<<cdiv(N, 16), TB, 0, stream>>>(bufA, W3, a3s, a3d, hb, als, ald, N);
    gat_node_kernel<8, 8, true><<<NODE_BLOCKS, TB, 0, stream>>>(hb, als, ald, offs, deg, csr_src, b3, bufA, N);

    // ---- layer 4: bufA -> hb -> d_out (H=1, D=16, no relu) ----
    gemm_logits_kernel<64, 16, 1><<<cdiv(N, 64), TB, 0, stream>>>(bufA, W4, a4s, a4d, hb, als, ald, N);
    gat_node_kernel<1, 16, false><<<NODE_BLOCKS, TB, 0, stream>>>(hb, als, ald, offs, deg, csr_src, b4, out, N);
}